// Round 16
// baseline (373.756 us; speedup 1.0000x reference)
//
#include <hip/hip_runtime.h>
#include <math.h>

#define LL 25600          // H*W
#define NTOTF 51200.f     // B*L (batch-norm N)
#define NSH 8             // stats shadow copies

using f16   = _Float16;
using f16x8 = __attribute__((ext_vector_type(8))) _Float16;
using f16x4 = __attribute__((ext_vector_type(4))) _Float16;
using f16x2 = __attribute__((ext_vector_type(2))) _Float16;
using f32x4 = __attribute__((ext_vector_type(4))) float;

// fast GELU: tanh form, one __expf.  max |err| vs exact erf-gelu ~1e-3.
__device__ __forceinline__ float gelu_f(float v) {
    const float u2 = v * (1.5957691216057308f + 0.0713548162726009f * v * v);
    const float e  = __expf(u2);
    return v * (1.f - 1.f / (e + 1.f));     // v * sigmoid(u2), inf-safe
}

// sum the NSH shadow copies of a [NSH][2C] stats array -> (mean, rstd)
__device__ __forceinline__ void stat_mr(const float* st, int C, int c,
                                        float& m, float& r) {
    float s1 = 0.f, s2 = 0.f;
#pragma unroll
    for (int sh = 0; sh < NSH; ++sh) {
        s1 += st[sh * 2 * C + c];
        s2 += st[sh * 2 * C + C + c];
    }
    m = s1 * (1.f / NTOTF);
    r = rsqrtf(s2 * (1.f / NTOTF) - m * m + 1e-5f);
}

// ---------------------------------------------------------------------------
// f16 MFMA GEMM (round-12 version; __launch_bounds__(512,2) = 128-VGPR budget).
// ---------------------------------------------------------------------------
template <int M, int K, int PP, int NSEG, bool IN32, bool LDG, bool TWOW,
          bool BIAS, bool STATS>
__global__ __launch_bounds__(512, 2) void gemm_kernel(
    const void* __restrict__ X1, const void* __restrict__ X2,
    const void* __restrict__ X3,
    const float* __restrict__ WA, const float* __restrict__ WB,
    const float* __restrict__ W2, const float* __restrict__ W3,
    const float* __restrict__ biasA, const float* __restrict__ biasB,
    const float* __restrict__ lstat,
    f16* __restrict__ Y1, f16* __restrict__ Y2, f16* __restrict__ Y3,
    float* __restrict__ ostat)
{
    constexpr int MR  = M / 128;
    constexpr int KS  = K / 32;
    constexpr int NR  = PP / 16;
    constexpr int PG  = PP / 8;
    constexpr int NCH = (K * PG) / 512;
    constexpr int NCHUNK = LL / PP;

    __shared__ f16 Xs[PP * K];

    const int tid  = threadIdx.x;
    const int lane = tid & 63;
    const int wv   = tid >> 6;
    const int lm16 = lane & 15, lg = lane >> 4;
    const int row0 = wv * (M / 8);

    int bx = blockIdx.x, seg = 0;
    if (NSEG > 1) { seg = bx / (2 * NCHUNK); bx -= seg * 2 * NCHUNK; }
    const int bb  = bx / NCHUNK;
    const int pp0 = (bx - bb * NCHUNK) * PP;

    const void*  Xp = (NSEG > 1) ? (seg == 0 ? X1 : (seg == 1 ? X2 : X3)) : X1;
    const float* Wp = (NSEG > 1) ? (seg == 0 ? WA : (seg == 1 ? W2 : W3)) : WA;
    f16*         Yp = (NSEG > 1) ? (seg == 0 ? Y1 : (seg == 1 ? Y2 : Y3)) : Y1;

    const int c0  = (tid / PG) * NCH;
    const int p0g = (tid % PG) * 8;

    f16x8 xin[NCH];
#pragma unroll
    for (int cc = 0; cc < NCH; ++cc) {
        const size_t roff = (size_t)(bb * K + c0 + cc) * LL + pp0 + p0g;
        if (IN32) {
            const float4 a  = *reinterpret_cast<const float4*>(
                                  reinterpret_cast<const float*>(Xp) + roff);
            const float4 b2 = *reinterpret_cast<const float4*>(
                                  reinterpret_cast<const float*>(Xp) + roff + 4);
            f16x8 v;
            v[0] = (f16)a.x;  v[1] = (f16)a.y;  v[2] = (f16)a.z;  v[3] = (f16)a.w;
            v[4] = (f16)b2.x; v[5] = (f16)b2.y; v[6] = (f16)b2.z; v[7] = (f16)b2.w;
            xin[cc] = v;
        } else {
            xin[cc] = *reinterpret_cast<const f16x8*>(
                          reinterpret_cast<const f16*>(Xp) + roff);
        }
    }

    f16x8 wfr[KS][MR];
#pragma unroll
    for (int k = 0; k < KS; ++k) {
        const int col = k * 32 + lg * 8;
#pragma unroll
        for (int mr = 0; mr < MR; ++mr) {
            const int row = row0 + mr * 16 + lm16;
            const float* wp = (TWOW && row >= 128)
                                  ? WB + (size_t)(row - 128) * K + col
                                  : Wp + (size_t)row * K + col;
            const float4 wa = *reinterpret_cast<const float4*>(wp);
            const float4 wb2 = *reinterpret_cast<const float4*>(wp + 4);
            f16x8 v;
            v[0] = (f16)wa.x; v[1] = (f16)wa.y; v[2] = (f16)wa.z; v[3] = (f16)wa.w;
            v[4] = (f16)wb2.x; v[5] = (f16)wb2.y; v[6] = (f16)wb2.z; v[7] = (f16)wb2.w;
            wfr[k][mr] = v;
        }
    }

    float bvv[MR], st1[MR], st2[MR];
#pragma unroll
    for (int mr = 0; mr < MR; ++mr) {
        const int o = row0 + mr * 16 + lm16;
        bvv[mr] = BIAS ? ((TWOW && o >= 128) ? biasB[o - 128] : biasA[o]) : 0.f;
        st1[mr] = 0.f; st2[mr] = 0.f;
    }

    if (LDG) {
#pragma unroll
        for (int cc = 0; cc < NCH; ++cc) {
            const int c = c0 + cc;
            float m, r;
            stat_mr(lstat, K, c, m, r);
#pragma unroll
            for (int j = 0; j < 8; ++j)
                xin[cc][j] = (f16)gelu_f(((float)xin[cc][j] - m) * r);
        }
    }

#pragma unroll
    for (int j = 0; j < 8; ++j) {
        const int pos = p0g + j;
        const int swz = ((pos & 7) ^ ((pos >> 3) & 7)) << 3;
        if constexpr (NCH == 8) {
            f16x8 v;
#pragma unroll
            for (int cc = 0; cc < 8; ++cc) v[cc] = xin[cc][j];
            *reinterpret_cast<f16x8*>(&Xs[(size_t)pos * K + (c0 ^ swz)]) = v;
        } else if constexpr (NCH == 4) {
            f16x4 v;
#pragma unroll
            for (int cc = 0; cc < 4; ++cc) v[cc] = xin[cc][j];
            *reinterpret_cast<f16x4*>(&Xs[(size_t)pos * K + (c0 ^ swz)]) = v;
        } else {
            f16x2 v;
#pragma unroll
            for (int cc = 0; cc < 2; ++cc) v[cc] = xin[cc][j];
            *reinterpret_cast<f16x2*>(&Xs[(size_t)pos * K + (c0 ^ swz)]) = v;
        }
    }
    __syncthreads();

    f32x4 acc[MR][NR];
#pragma unroll
    for (int mr = 0; mr < MR; ++mr)
#pragma unroll
        for (int nr = 0; nr < NR; ++nr)
            acc[mr][nr] = (f32x4){0.f, 0.f, 0.f, 0.f};

#pragma unroll
    for (int k = 0; k < KS; ++k) {
        const int kc = k * 32 + lg * 8;
        f16x8 xa[NR];
#pragma unroll
        for (int nr = 0; nr < NR; ++nr) {
            const int pos = nr * 16 + lm16;
            const int swz = ((pos & 7) ^ ((pos >> 3) & 7)) << 3;
            xa[nr] = *reinterpret_cast<const f16x8*>(
                &Xs[(size_t)pos * K + (kc ^ swz)]);
        }
#pragma unroll
        for (int mr = 0; mr < MR; ++mr)
#pragma unroll
            for (int nr = 0; nr < NR; ++nr)
                acc[mr][nr] = __builtin_amdgcn_mfma_f32_16x16x32_f16(
                    xa[nr], wfr[k][mr], acc[mr][nr], 0, 0, 0);
    }

#pragma unroll
    for (int mr = 0; mr < MR; ++mr) {
        const int o = row0 + mr * 16 + lm16;
        f16* yb = Yp + (size_t)(bb * M + o) * LL + pp0;
#pragma unroll
        for (int nr = 0; nr < NR; ++nr) {
            f16x4 o4;
#pragma unroll
            for (int r = 0; r < 4; ++r) {
                const float v = acc[mr][nr][r] + bvv[mr];
                o4[r] = (f16)v;
                if (STATS) { st1[mr] += v; st2[mr] += v * v; }
            }
            *reinterpret_cast<f16x4*>(yb + nr * 16 + lg * 4) = o4;
        }
    }

    if (STATS) {
        float* osb = ostat + (size_t)(blockIdx.x & (NSH - 1)) * 2 * M;
#pragma unroll
        for (int mr = 0; mr < MR; ++mr) {
            float s1 = st1[mr], s2 = st2[mr];
            s1 += __shfl_xor(s1, 16); s2 += __shfl_xor(s2, 16);
            s1 += __shfl_xor(s1, 32); s2 += __shfl_xor(s2, 32);
            if (lane < 16) {
                const int o = row0 + mr * 16 + lm16;
                atomicAdd(&osb[o], s1);
                atomicAdd(&osb[M + o], s2);
            }
        }
    }
}

// ---------------------------------------------------------------------------
// Activation pass: actq = gelu(bn(qraw)), actkv = gelu(bn(kvraw)).
// One f16x8 chunk per thread; grid 9600 x 256.
// ---------------------------------------------------------------------------
__global__ __launch_bounds__(256) void act_kernel(
    const f16* __restrict__ qraw, const f16* __restrict__ kvraw,
    const float* __restrict__ sQ, const float* __restrict__ sKV,
    f16* __restrict__ actq, f16* __restrict__ actkv)
{
    const int idx = blockIdx.x * 256 + threadIdx.x;
    const f16* src; f16* dst; const float* st; int C, local;
    if (idx < 819200) { src = qraw;  dst = actq;  st = sQ;  C = 128; local = idx; }
    else              { src = kvraw; dst = actkv; st = sKV; C = 256; local = idx - 819200; }
    const int c = (local / 3200) % C;
    float m, r;
    stat_mr(st, C, c, m, r);
    const f16x8 v = *reinterpret_cast<const f16x8*>(src + (size_t)local * 8);
    f16x8 o;
#pragma unroll
    for (int j = 0; j < 8; ++j)
        o[j] = (f16)gelu_f(((float)v[j] - m) * r);
    *reinterpret_cast<f16x8*>(dst + (size_t)local * 8) = o;
}

// ---------------------------------------------------------------------------
// Batched depthwise 5x5 SAME on PRE-ACTIVATED f16 input, FULL-WIDTH row tiles.
// Tile = 160 (full W) x 8 rows; halo = 12 full rows staged via coalesced
// f16x2 loads into LDS [12][164] (2-col zero pads).  Thread computes 5
// consecutive outputs (fp32 acc).  grid (1, 20, 768): y = row-tile,
// z/256 selects branch (q / k / v), z%256 = (b,c).
// ---------------------------------------------------------------------------
__global__ __launch_bounds__(256) void dw5_kernel(
    const f16* __restrict__ actq, const f16* __restrict__ actkv,
    const float* __restrict__ dwq, const float* __restrict__ dwk,
    const float* __restrict__ dwv,
    f16* __restrict__ oq, f16* __restrict__ ok, f16* __restrict__ ov)
{
    __shared__ f16 pt[12][164];
    const int z = blockIdx.z;
    const int which = z >> 8;
    const int bc = z & 255;
    const int b = bc >> 7, c = bc & 127;

    const f16* src; const float* wdwp; f16* outp;
    if (which == 0)      { src = actq  + (size_t)(b * 128 + c) * LL;       wdwp = dwq + c * 25; outp = oq; }
    else if (which == 1) { src = actkv + (size_t)(b * 256 + c) * LL;       wdwp = dwk + c * 25; outp = ok; }
    else                 { src = actkv + (size_t)(b * 256 + 128 + c) * LL; wdwp = dwv + c * 25; outp = ov; }

    const int h0 = blockIdx.y * 8;
    const int tid = threadIdx.x;

    // per-thread weights (wave-uniform scalar loads)
    float wr[25];
#pragma unroll
    for (int q = 0; q < 25; ++q) wr[q] = wdwp[q];

    // zero the 2-col side pads (12 rows x {0,1,162,163})
    if (tid < 48) {
        const int t = tid >> 2, k = tid & 3;
        pt[t][(k < 2) ? k : 160 + k] = (f16)0;
    }
    // stage 12 full rows as f16x2 (80 pairs/row)
    for (int idx = tid; idx < 960; idx += 256) {
        const int t = idx / 80, j = idx - t * 80;
        const int ih = h0 - 2 + t;
        f16x2 v;
        if (ih >= 0 && ih < 160)
            v = *reinterpret_cast<const f16x2*>(src + ih * 160 + j * 2);
        else { v[0] = (f16)0; v[1] = (f16)0; }
        *reinterpret_cast<f16x2*>(&pt[t][2 + j * 2]) = v;
    }
    __syncthreads();

    // thread -> y = tid>>5 (0..7), 5 consecutive outputs at x0 = (tid&31)*5
    const int y  = tid >> 5;
    const int x0 = (tid & 31) * 5;

    float acc[5] = {0.f, 0.f, 0.f, 0.f, 0.f};
#pragma unroll
    for (int u = 0; u < 5; ++u) {
        const f16* row = &pt[y + u][x0];
        float r[9];
#pragma unroll
        for (int j = 0; j < 9; ++j) r[j] = (float)row[j];
#pragma unroll
        for (int v = 0; v < 5; ++v) {
            const float wv = wr[u * 5 + v];
#pragma unroll
            for (int i = 0; i < 5; ++i)
                acc[i] = fmaf(wv, r[v + i], acc[i]);
        }
    }

    f16* ob = outp + (size_t)(b * 128 + c) * LL + (size_t)(h0 + y) * 160 + x0;
#pragma unroll
    for (int i = 0; i < 5; ++i) ob[i] = (f16)acc[i];
}

// ---------------------------------------------------------------------------
// Attention reduce via MFMA outer product (inputs pre-activated; relu only).
// grid 800 = (b:2, h:16, chunk:25 of 1024 pos), block 256 (4 waves).
// ---------------------------------------------------------------------------
__global__ __launch_bounds__(256) void att_reduce_kernel(
    const f16* __restrict__ ACT, const f16* __restrict__ K2,
    const f16* __restrict__ V2,
    float* __restrict__ kvout, float* __restrict__ ksum)
{
    __shared__ float kvred[4][256];

    const int bx = blockIdx.x;
    const int b = bx / 400;
    const int rem = bx - b * 400;
    const int h = rem / 25;
    const int chunk = rem - h * 25;
    const int tid = threadIdx.x;
    const int wv = tid >> 6, l = tid & 63;
    const int ch = l & 15, kg = l >> 4;
    const bool half1 = h < 8;

    const f16* kbase = half1 ? ACT + (size_t)(b * 256 + h * 16 + ch) * LL
                             : K2 + (size_t)(b * 128 + (h - 8) * 16 + ch) * LL;
    const f16* vbase = half1 ? ACT + (size_t)(b * 256 + 128 + h * 16 + ch) * LL
                             : V2 + (size_t)(b * 128 + (h - 8) * 16 + ch) * LL;

    f32x4 acc = (f32x4){0.f, 0.f, 0.f, 0.f};
    float ksacc = 0.f;
    const int base = chunk * 1024 + kg * 8;
#pragma unroll
    for (int it = 0; it < 8; ++it) {
        const int p = base + wv * 256 + it * 32;
        const f16x8 kf = *reinterpret_cast<const f16x8*>(kbase + p);
        const f16x8 vf = *reinterpret_cast<const f16x8*>(vbase + p);
        f16x8 ka;
#pragma unroll
        for (int j = 0; j < 8; ++j) {
            const f16 kv_ = kf[j];
            ka[j] = (kv_ > (f16)0) ? kv_ : (f16)0;
            ksacc += (float)ka[j];
        }
        acc = __builtin_amdgcn_mfma_f32_16x16x32_f16(ka, vf, acc, 0, 0, 0);
    }

    constexpr float s = 1.f / (float)LL;
#pragma unroll
    for (int r = 0; r < 4; ++r)
        kvred[wv][(kg * 4 + r) * 16 + ch] = acc[r];
    __syncthreads();
    {
        float t = kvred[0][tid] + kvred[1][tid] + kvred[2][tid] + kvred[3][tid];
        atomicAdd(&kvout[(size_t)(b * 16 + h) * 256 + tid], t * s);
    }

    float s1 = ksacc;
    s1 += __shfl_xor(s1, 16);
    s1 += __shfl_xor(s1, 32);
    if (l < 16) atomicAdd(&ksum[(size_t)(b * 16 + h) * 16 + ch], s1 * s);
}

// ---------------------------------------------------------------------------
// Attention apply (inputs pre-activated; relu only).
// grid 3200 = (b:2, h:16, chunk:100 of 256 pos), block 256.
// ---------------------------------------------------------------------------
__global__ __launch_bounds__(256) void att_apply_kernel(
    const f16* __restrict__ Q, const f16* __restrict__ Q2,
    const float* __restrict__ kvin, const float* __restrict__ ksumin,
    f16* __restrict__ att)
{
    __shared__ float kvs[256];
    __shared__ float kss[16];

    const int bx = blockIdx.x;
    const int b = bx / 1600;
    const int rem = bx - b * 1600;
    const int h = rem / 100;
    const int chunk = rem - h * 100;
    const int tid = threadIdx.x;
    const int p = chunk * 256 + tid;

    kvs[tid] = kvin[(size_t)b * 4096 + h * 256 + tid];
    if (tid < 16) kss[tid] = ksumin[(size_t)b * 256 + h * 16 + tid];
    __syncthreads();

    const f16* qb = (h < 8) ? Q + (size_t)(b * 128 + h * 16) * LL
                            : Q2 + (size_t)(b * 128 + (h - 8) * 16) * LL;
    float s[16];
#pragma unroll
    for (int d = 0; d < 16; ++d)
        s[d] = fmaxf((float)qb[(size_t)d * LL + p], 0.f);
    float denom = 0.f;
#pragma unroll
    for (int d = 0; d < 16; ++d) denom = fmaf(s[d], kss[d], denom);
    const float z = 1.f / fmaxf(denom, 1e-6f);

    f16* ob = att + (size_t)(b * 256 + h * 16) * LL + p;
#pragma unroll
    for (int e = 0; e < 16; ++e) {
        float acc = 0.f;
#pragma unroll
        for (int d = 0; d < 16; ++d)
            acc = fmaf(s[d], kvs[d * 16 + e], acc);
        ob[(size_t)e * LL] = (f16)(acc * z);
    }
}

// ---------------------------------------------------------------------------
// Fused tail: t[c] = resid + gelu(bn(yconv)); out = LN_c(t)*w+b.
// VECTORIZED (round-14 version): thread handles 8 consecutive positions.
// ---------------------------------------------------------------------------
template <bool RES32, bool OUT32>
__global__ __launch_bounds__(256) void fuse_ln_kernel(
    const f16* __restrict__ yconv, const void* __restrict__ residv,
    const float* __restrict__ stat,
    const float* __restrict__ lnw, const float* __restrict__ lnb,
    void* __restrict__ outv)
{
    __shared__ float t[128][65];
    __shared__ float mrs[128][2];
    __shared__ float red[4][64][2];
    __shared__ float mln[64], rln[64];

    const int bx = blockIdx.x;
    const int b = bx / 400, p0 = (bx - b * 400) * 64;
    const int tid = threadIdx.x;

    if (tid < 128) {
        float m, r;
        stat_mr(stat, 128, tid, m, r);
        mrs[tid][0] = m; mrs[tid][1] = r;
    }
    __syncthreads();

#pragma unroll
    for (int it = 0; it < 4; ++it) {
        const int chunk = it * 256 + tid;
        const int c  = chunk >> 3;
        const int pg = (chunk & 7) * 8;
        const size_t off = (size_t)(b * 128 + c) * LL + p0 + pg;
        const f16x8 yv = *reinterpret_cast<const f16x8*>(yconv + off);
        const float m = mrs[c][0], r = mrs[c][1];
        float rv[8];
        if (RES32) {
            const float* rp = reinterpret_cast<const float*>(residv) + off;
            const float4 ra = *reinterpret_cast<const float4*>(rp);
            const float4 rb = *reinterpret_cast<const float4*>(rp + 4);
            rv[0] = ra.x; rv[1] = ra.y; rv[2] = ra.z; rv[3] = ra.w;
            rv[4] = rb.x; rv[5] = rb.y; rv[6] = rb.z; rv[7] = rb.w;
        } else {
            const f16x8 rr = *reinterpret_cast<const f16x8*>(
                reinterpret_cast<const f16*>(residv) + off);
#pragma unroll
            for (int j = 0; j < 8; ++j) rv[j] = (float)rr[j];
        }
#pragma unroll
        for (int j = 0; j < 8; ++j)
            t[c][pg + j] = gelu_f(((float)yv[j] - m) * r) + rv[j];
    }
    __syncthreads();

    {
        const int i = tid & 63, q = tid >> 6;
        float ps = 0.f, pq = 0.f;
        for (int c = q * 32; c < q * 32 + 32; ++c) {
            const float v = t[c][i];
            ps += v; pq += v * v;
        }
        red[q][i][0] = ps; red[q][i][1] = pq;
    }
    __syncthreads();
    if (tid < 64) {
        float s1 = 0.f, s2 = 0.f;
#pragma unroll
        for (int q = 0; q < 4; ++q) { s1 += red[q][tid][0]; s2 += red[q][tid][1]; }
        const float m = s1 * (1.f / 128.f);
        const float var = s2 * (1.f / 128.f) - m * m;
        mln[tid] = m; rln[tid] = rsqrtf(var + 1e-5f);
    }
    __syncthreads();

#pragma unroll
    for (int it = 0; it < 4; ++it) {
        const int chunk = it * 256 + tid;
        const int c  = chunk >> 3;
        const int pg = (chunk & 7) * 8;
        const size_t off = (size_t)(b * 128 + c) * LL + p0 + pg;
        const float lw = lnw[c], lb = lnb[c];
        if (OUT32) {
            float4 oa, ob2;
            float* op = reinterpret_cast<float*>(outv) + off;
            oa.x = (t[c][pg+0] - mln[pg+0]) * rln[pg+0] * lw + lb;
            oa.y = (t[c][pg+1] - mln[pg+1]) * rln[pg+1] * lw + lb;
            oa.z = (t[c][pg+2] - mln[pg+2]) * rln[pg+2] * lw + lb;
            oa.w = (t[c][pg+3] - mln[pg+3]) * rln[pg+3] * lw + lb;
            ob2.x = (t[c][pg+4] - mln[pg+4]) * rln[pg+4] * lw + lb;
            ob2.y = (t[c][pg+5] - mln[pg+5]) * rln[pg+5] * lw + lb;
            ob2.z = (t[c][pg+6] - mln[pg+6]) * rln[pg+6] * lw + lb;
            ob2.w = (t[c][pg+7] - mln[pg+7]) * rln[pg+7] * lw + lb;
            *reinterpret_cast<float4*>(op) = oa;
            *reinterpret_cast<float4*>(op + 4) = ob2;
        } else {
            f16x8 o;
#pragma unroll
            for (int j = 0; j < 8; ++j)
                o[j] = (f16)((t[c][pg + j] - mln[pg + j]) * rln[pg + j] * lw + lb);
            *reinterpret_cast<f16x8*>(reinterpret_cast<f16*>(outv) + off) = o;
        }
    }
}

// ---------------------------------------------------------------------------
// wcomb[o, c2] = sum_m wmerge[o, m] * wproj[m, c2]  +  zero the stats region.
// grid 128 x 256 (32768 threads >= zcount).
// ---------------------------------------------------------------------------
__global__ __launch_bounds__(256) void wcomb_kernel(
    const float* __restrict__ wmerge, const float* __restrict__ wproj,
    float* __restrict__ wc, float* __restrict__ zbase, int zcount)
{
    const int g = blockIdx.x * 256 + threadIdx.x;
    if (g < zcount) zbase[g] = 0.f;

    const int o = blockIdx.x;
    const int c2 = threadIdx.x;
    float acc = 0.f;
#pragma unroll 4
    for (int m = 0; m < 128; ++m)
        acc = fmaf(wmerge[o * 128 + m], wproj[m * 256 + c2], acc);
    wc[o * 256 + c2] = acc;
}

// ---------------------------------------------------------------------------
extern "C" void kernel_launch(void* const* d_in, const int* in_sizes, int n_in,
                              void* d_out, int out_size, void* d_ws, size_t ws_size,
                              hipStream_t stream)
{
    const float* x      = (const float*)d_in[0];
    const float* source = (const float*)d_in[1];
    const float* wq = (const float*)d_in[2];  const float* bq = (const float*)d_in[3];
    const float* wk = (const float*)d_in[4];  const float* bk = (const float*)d_in[5];
    const float* wvw = (const float*)d_in[6]; const float* bvb = (const float*)d_in[7];
    const float* dwq = (const float*)d_in[8];  const float* pwq = (const float*)d_in[9];
    const float* dwk = (const float*)d_in[10]; const float* pwk = (const float*)d_in[11];
    const float* dwv = (const float*)d_in[12]; const float* pwv = (const float*)d_in[13];
    const float* wproj  = (const float*)d_in[14];
    const float* wmerge = (const float*)d_in[15]; const float* bmerge = (const float*)d_in[16];
    const float* wff1 = (const float*)d_in[17]; const float* bff1 = (const float*)d_in[18];
    const float* wff2 = (const float*)d_in[19]; const float* bff2 = (const float*)d_in[20];
    const float* ln1w = (const float*)d_in[21]; const float* ln1b = (const float*)d_in[22];
    const float* ln2w = (const float*)d_in[23]; const float* ln2b = (const float*)d_in[24];

    const size_t UNIT  = (size_t)2 * 128 * LL;                // 6,553,600 f16
    const size_t UNITB = UNIT * sizeof(f16);                  // 13,107,200 B
    char* w = (char*)d_ws;
    f16* qraw  = (f16*)w; w += UNITB;        // later: dtq
    f16* kvraw = (f16*)w; w += 2 * UNITB;    // later: dtk, dtv
    f16* actq  = (f16*)w; w += UNITB;
    f16* actkv = (f16*)w; w += 2 * UNITB;    // later: att
    f16* q2raw = (f16*)w; w += UNITB;
    f16* k2raw = (f16*)w; w += UNITB;
    f16* v2raw = (f16*)w; w += UNITB;
    f16* y2raw = (f16*)w; w += UNITB;
    f16* msg   = (f16*)w; w += UNITB;
    f16* ff1raw= (f16*)w; w += 2 * UNITB;
    f16* ff2raw= (f16*)w; w += UNITB;

    f16* dtq = qraw;
    f16* dtk = kvraw;
    f16* dtv = kvraw + UNIT;
    f16* att = actkv;

    float* zbase = (float*)w;
    float* kvred = zbase;                      // 8192
    float* ksum  = zbase + 8192;               // 512
    float* sQ    = zbase + 8704;               // NSH*256
    float* sKV   = sQ + NSH * 256;             // NSH*512
    float* sM    = sKV + NSH * 512;            // NSH*256
    float* sF1   = sM + NSH * 256;             // NSH*512
    float* sF2   = sF1 + NSH * 512;            // NSH*256
    const int zcount = 8192 + 512 + NSH * (256 + 512 + 256 + 512 + 256); // 23040
    float* wcomb = zbase + zcount;             // 128*256 fp32

    // zero stats + combine wproj/wmerge in one launch
    wcomb_kernel<<<128, 256, 0, stream>>>(wmerge, wproj, wcomb, zbase, zcount);

    // q / (k,v) 1x1 convs with BN stats  <M,K,PP,NSEG,IN32,LDG,TWOW,BIAS,STATS>
    gemm_kernel<128,128,128,1,true,false,false,true,true><<<400, 512, 0, stream>>>(
        x, nullptr, nullptr, wq, nullptr, nullptr, nullptr, bq, nullptr, nullptr,
        qraw, nullptr, nullptr, sQ);
    gemm_kernel<256,128,64,1,true,false,true,true,true><<<800, 512, 0, stream>>>(
        source, nullptr, nullptr, wk, wvw, nullptr, nullptr, bk, bvb, nullptr,
        kvraw, nullptr, nullptr, sKV);

    // materialize activations once (consumed by dw5 / att_reduce / att_apply)
    act_kernel<<<9600, 256, 0, stream>>>(qraw, kvraw, sQ, sKV, actq, actkv);

    // multiscale branch: 3 depthwise in one launch, 3 pointwise in one launch
    dim3 dwg(1, 20, 768);
    dw5_kernel<<<dwg, 256, 0, stream>>>(actq, actkv, dwq, dwk, dwv, dtq, dtk, dtv);
    gemm_kernel<128,128,128,3,false,false,false,false,false><<<1200, 512, 0, stream>>>(
        dtq, dtk, dtv, pwq, nullptr, pwk, pwv, nullptr, nullptr, nullptr,
        q2raw, k2raw, v2raw, nullptr);

    // linear attention
    att_reduce_kernel<<<800, 256, 0, stream>>>(actkv, k2raw, v2raw, kvred, ksum);
    att_apply_kernel<<<3200, 256, 0, stream>>>(actq, q2raw, kvred, ksum, att);

    // merged (wmerge @ wproj) conv with BN stats
    gemm_kernel<128,256,128,1,false,false,false,true,true><<<400, 512, 0, stream>>>(
        att, nullptr, nullptr, wcomb, nullptr, nullptr, nullptr, bmerge, nullptr,
        nullptr, y2raw, nullptr, nullptr, sM);

    // msg = LN1(x + gelu(bn(y2)))
    fuse_ln_kernel<true,false><<<800, 256, 0, stream>>>(
        y2raw, x, sM, ln1w, ln1b, msg);

    // FFN: ff1 GEMM; ff2 GEMM with BN+GELU fused on load
    gemm_kernel<256,128,64,1,false,false,false,true,true><<<800, 512, 0, stream>>>(
        msg, nullptr, nullptr, wff1, nullptr, nullptr, nullptr, bff1, nullptr,
        nullptr, ff1raw, nullptr, nullptr, sF1);
    gemm_kernel<128,256,128,1,false,true,false,true,true><<<400, 512, 0, stream>>>(
        ff1raw, nullptr, nullptr, wff2, nullptr, nullptr, nullptr, bff2, nullptr,
        sF1, ff2raw, nullptr, nullptr, sF2);

    // out = LN2(msg + gelu(bn(ff2)))
    fuse_ln_kernel<false,true><<<800, 256, 0, stream>>>(
        ff2raw, msg, sF2, ln2w, ln2b, (float*)d_out);
}

// Round 17
// 254.436 us; speedup vs baseline: 1.4690x; 1.4690x over previous
//
#include <hip/hip_runtime.h>
#include <math.h>

#define LL 25600          // H*W
#define NTOTF 51200.f     // B*L (batch-norm N)
#define NSH 8             // stats shadow copies

using f16   = _Float16;
using f16x8 = __attribute__((ext_vector_type(8))) _Float16;
using f16x4 = __attribute__((ext_vector_type(4))) _Float16;
using f16x2 = __attribute__((ext_vector_type(2))) _Float16;
using f32x4 = __attribute__((ext_vector_type(4))) float;

// fast GELU: tanh form, one __expf.  max |err| vs exact erf-gelu ~1e-3.
__device__ __forceinline__ float gelu_f(float v) {
    const float u2 = v * (1.5957691216057308f + 0.0713548162726009f * v * v);
    const float e  = __expf(u2);
    return v * (1.f - 1.f / (e + 1.f));     // v * sigmoid(u2), inf-safe
}

// sum the NSH shadow copies of a [NSH][2C] stats array -> (mean, rstd)
__device__ __forceinline__ void stat_mr(const float* st, int C, int c,
                                        float& m, float& r) {
    float s1 = 0.f, s2 = 0.f;
#pragma unroll
    for (int sh = 0; sh < NSH; ++sh) {
        s1 += st[sh * 2 * C + c];
        s2 += st[sh * 2 * C + C + c];
    }
    m = s1 * (1.f / NTOTF);
    r = rsqrtf(s2 * (1.f / NTOTF) - m * m + 1e-5f);
}

// ---------------------------------------------------------------------------
// f16 MFMA GEMM (round-12 version; __launch_bounds__(512,2) = 128-VGPR budget).
// ---------------------------------------------------------------------------
template <int M, int K, int PP, int NSEG, bool IN32, bool LDG, bool TWOW,
          bool BIAS, bool STATS>
__global__ __launch_bounds__(512, 2) void gemm_kernel(
    const void* __restrict__ X1, const void* __restrict__ X2,
    const void* __restrict__ X3,
    const float* __restrict__ WA, const float* __restrict__ WB,
    const float* __restrict__ W2, const float* __restrict__ W3,
    const float* __restrict__ biasA, const float* __restrict__ biasB,
    const float* __restrict__ lstat,
    f16* __restrict__ Y1, f16* __restrict__ Y2, f16* __restrict__ Y3,
    float* __restrict__ ostat)
{
    constexpr int MR  = M / 128;
    constexpr int KS  = K / 32;
    constexpr int NR  = PP / 16;
    constexpr int PG  = PP / 8;
    constexpr int NCH = (K * PG) / 512;
    constexpr int NCHUNK = LL / PP;

    __shared__ f16 Xs[PP * K];

    const int tid  = threadIdx.x;
    const int lane = tid & 63;
    const int wv   = tid >> 6;
    const int lm16 = lane & 15, lg = lane >> 4;
    const int row0 = wv * (M / 8);

    int bx = blockIdx.x, seg = 0;
    if (NSEG > 1) { seg = bx / (2 * NCHUNK); bx -= seg * 2 * NCHUNK; }
    const int bb  = bx / NCHUNK;
    const int pp0 = (bx - bb * NCHUNK) * PP;

    const void*  Xp = (NSEG > 1) ? (seg == 0 ? X1 : (seg == 1 ? X2 : X3)) : X1;
    const float* Wp = (NSEG > 1) ? (seg == 0 ? WA : (seg == 1 ? W2 : W3)) : WA;
    f16*         Yp = (NSEG > 1) ? (seg == 0 ? Y1 : (seg == 1 ? Y2 : Y3)) : Y1;

    const int c0  = (tid / PG) * NCH;
    const int p0g = (tid % PG) * 8;

    f16x8 xin[NCH];
#pragma unroll
    for (int cc = 0; cc < NCH; ++cc) {
        const size_t roff = (size_t)(bb * K + c0 + cc) * LL + pp0 + p0g;
        if (IN32) {
            const float4 a  = *reinterpret_cast<const float4*>(
                                  reinterpret_cast<const float*>(Xp) + roff);
            const float4 b2 = *reinterpret_cast<const float4*>(
                                  reinterpret_cast<const float*>(Xp) + roff + 4);
            f16x8 v;
            v[0] = (f16)a.x;  v[1] = (f16)a.y;  v[2] = (f16)a.z;  v[3] = (f16)a.w;
            v[4] = (f16)b2.x; v[5] = (f16)b2.y; v[6] = (f16)b2.z; v[7] = (f16)b2.w;
            xin[cc] = v;
        } else {
            xin[cc] = *reinterpret_cast<const f16x8*>(
                          reinterpret_cast<const f16*>(Xp) + roff);
        }
    }

    f16x8 wfr[KS][MR];
#pragma unroll
    for (int k = 0; k < KS; ++k) {
        const int col = k * 32 + lg * 8;
#pragma unroll
        for (int mr = 0; mr < MR; ++mr) {
            const int row = row0 + mr * 16 + lm16;
            const float* wp = (TWOW && row >= 128)
                                  ? WB + (size_t)(row - 128) * K + col
                                  : Wp + (size_t)row * K + col;
            const float4 wa = *reinterpret_cast<const float4*>(wp);
            const float4 wb2 = *reinterpret_cast<const float4*>(wp + 4);
            f16x8 v;
            v[0] = (f16)wa.x; v[1] = (f16)wa.y; v[2] = (f16)wa.z; v[3] = (f16)wa.w;
            v[4] = (f16)wb2.x; v[5] = (f16)wb2.y; v[6] = (f16)wb2.z; v[7] = (f16)wb2.w;
            wfr[k][mr] = v;
        }
    }

    float bvv[MR], st1[MR], st2[MR];
#pragma unroll
    for (int mr = 0; mr < MR; ++mr) {
        const int o = row0 + mr * 16 + lm16;
        bvv[mr] = BIAS ? ((TWOW && o >= 128) ? biasB[o - 128] : biasA[o]) : 0.f;
        st1[mr] = 0.f; st2[mr] = 0.f;
    }

    if (LDG) {
#pragma unroll
        for (int cc = 0; cc < NCH; ++cc) {
            const int c = c0 + cc;
            float m, r;
            stat_mr(lstat, K, c, m, r);
#pragma unroll
            for (int j = 0; j < 8; ++j)
                xin[cc][j] = (f16)gelu_f(((float)xin[cc][j] - m) * r);
        }
    }

#pragma unroll
    for (int j = 0; j < 8; ++j) {
        const int pos = p0g + j;
        const int swz = ((pos & 7) ^ ((pos >> 3) & 7)) << 3;
        if constexpr (NCH == 8) {
            f16x8 v;
#pragma unroll
            for (int cc = 0; cc < 8; ++cc) v[cc] = xin[cc][j];
            *reinterpret_cast<f16x8*>(&Xs[(size_t)pos * K + (c0 ^ swz)]) = v;
        } else if constexpr (NCH == 4) {
            f16x4 v;
#pragma unroll
            for (int cc = 0; cc < 4; ++cc) v[cc] = xin[cc][j];
            *reinterpret_cast<f16x4*>(&Xs[(size_t)pos * K + (c0 ^ swz)]) = v;
        } else {
            f16x2 v;
#pragma unroll
            for (int cc = 0; cc < 2; ++cc) v[cc] = xin[cc][j];
            *reinterpret_cast<f16x2*>(&Xs[(size_t)pos * K + (c0 ^ swz)]) = v;
        }
    }
    __syncthreads();

    f32x4 acc[MR][NR];
#pragma unroll
    for (int mr = 0; mr < MR; ++mr)
#pragma unroll
        for (int nr = 0; nr < NR; ++nr)
            acc[mr][nr] = (f32x4){0.f, 0.f, 0.f, 0.f};

#pragma unroll
    for (int k = 0; k < KS; ++k) {
        const int kc = k * 32 + lg * 8;
        f16x8 xa[NR];
#pragma unroll
        for (int nr = 0; nr < NR; ++nr) {
            const int pos = nr * 16 + lm16;
            const int swz = ((pos & 7) ^ ((pos >> 3) & 7)) << 3;
            xa[nr] = *reinterpret_cast<const f16x8*>(
                &Xs[(size_t)pos * K + (kc ^ swz)]);
        }
#pragma unroll
        for (int mr = 0; mr < MR; ++mr)
#pragma unroll
            for (int nr = 0; nr < NR; ++nr)
                acc[mr][nr] = __builtin_amdgcn_mfma_f32_16x16x32_f16(
                    xa[nr], wfr[k][mr], acc[mr][nr], 0, 0, 0);
    }

#pragma unroll
    for (int mr = 0; mr < MR; ++mr) {
        const int o = row0 + mr * 16 + lm16;
        f16* yb = Yp + (size_t)(bb * M + o) * LL + pp0;
#pragma unroll
        for (int nr = 0; nr < NR; ++nr) {
            f16x4 o4;
#pragma unroll
            for (int r = 0; r < 4; ++r) {
                const float v = acc[mr][nr][r] + bvv[mr];
                o4[r] = (f16)v;
                if (STATS) { st1[mr] += v; st2[mr] += v * v; }
            }
            *reinterpret_cast<f16x4*>(yb + nr * 16 + lg * 4) = o4;
        }
    }

    if (STATS) {
        float* osb = ostat + (size_t)(blockIdx.x & (NSH - 1)) * 2 * M;
#pragma unroll
        for (int mr = 0; mr < MR; ++mr) {
            float s1 = st1[mr], s2 = st2[mr];
            s1 += __shfl_xor(s1, 16); s2 += __shfl_xor(s2, 16);
            s1 += __shfl_xor(s1, 32); s2 += __shfl_xor(s2, 32);
            if (lane < 16) {
                const int o = row0 + mr * 16 + lm16;
                atomicAdd(&osb[o], s1);
                atomicAdd(&osb[M + o], s2);
            }
        }
    }
}

// ---------------------------------------------------------------------------
// Activation pass: actq = gelu(bn(qraw)), actkv = gelu(bn(kvraw)).
// One f16x8 chunk per thread; grid 9600 x 256.
// ---------------------------------------------------------------------------
__global__ __launch_bounds__(256) void act_kernel(
    const f16* __restrict__ qraw, const f16* __restrict__ kvraw,
    const float* __restrict__ sQ, const float* __restrict__ sKV,
    f16* __restrict__ actq, f16* __restrict__ actkv)
{
    const int idx = blockIdx.x * 256 + threadIdx.x;
    const f16* src; f16* dst; const float* st; int C, local;
    if (idx < 819200) { src = qraw;  dst = actq;  st = sQ;  C = 128; local = idx; }
    else              { src = kvraw; dst = actkv; st = sKV; C = 256; local = idx - 819200; }
    const int c = (local / 3200) % C;
    float m, r;
    stat_mr(st, C, c, m, r);
    const f16x8 v = *reinterpret_cast<const f16x8*>(src + (size_t)local * 8);
    f16x8 o;
#pragma unroll
    for (int j = 0; j < 8; ++j)
        o[j] = (f16)gelu_f(((float)v[j] - m) * r);
    *reinterpret_cast<f16x8*>(dst + (size_t)local * 8) = o;
}

// ---------------------------------------------------------------------------
// Batched depthwise 5x5 SAME on PRE-ACTIVATED f16 input (round-10/14 version).
// 32x32 output tile; LDS holds vertically-packed f16x2 rows (y, y+16).
// Per thread: 2 horizontal x 2 vertical outputs via v_pk_fma_f16.
// grid (5,5,768): z/256 selects branch (q / k / v), z%256 = (b,c).
// ---------------------------------------------------------------------------
__global__ __launch_bounds__(256) void dw5_kernel(
    const f16* __restrict__ actq, const f16* __restrict__ actkv,
    const float* __restrict__ dwq, const float* __restrict__ dwk,
    const float* __restrict__ dwv,
    f16* __restrict__ oq, f16* __restrict__ ok, f16* __restrict__ ov)
{
    __shared__ f16x2 pt[20][41];
    const int z = blockIdx.z;
    const int which = z >> 8;
    const int bc = z & 255;
    const int b = bc >> 7, c = bc & 127;

    const f16* src; const float* wdwp; f16* outp;
    if (which == 0)      { src = actq  + (size_t)(b * 128 + c) * LL;       wdwp = dwq + c * 25; outp = oq; }
    else if (which == 1) { src = actkv + (size_t)(b * 256 + c) * LL;       wdwp = dwk + c * 25; outp = ok; }
    else                 { src = actkv + (size_t)(b * 256 + 128 + c) * LL; wdwp = dwv + c * 25; outp = ov; }

    const int h0 = blockIdx.y * 32, w0 = blockIdx.x * 32;
    const int tid = threadIdx.x;

    f16x2 wp[25];
#pragma unroll
    for (int q = 0; q < 25; ++q) {
        const f16 wv16 = (f16)wdwp[q];
        wp[q][0] = wv16; wp[q][1] = wv16;
    }

    for (int idx = tid; idx < 720; idx += 256) {
        const int t  = idx / 36, cc = idx - t * 36;
        const int iw = w0 - 2 + cc;
        const int ih0 = h0 - 2 + t, ih1 = ih0 + 16;
        const int iwc  = min(max(iw, 0), 159);
        const int ihc0 = min(max(ih0, 0), 159);
        const int ihc1 = min(max(ih1, 0), 159);
        const bool okw = (iw >= 0) & (iw < 160);
        f16 lo = src[ihc0 * 160 + iwc];
        f16 hi = src[ihc1 * 160 + iwc];
        if (!(okw & (ih0 >= 0) & (ih0 < 160))) lo = (f16)0;
        if (!(okw & (ih1 >= 0) & (ih1 < 160))) hi = (f16)0;
        f16x2 pv; pv[0] = lo; pv[1] = hi;
        pt[t][cc] = pv;
    }
    __syncthreads();

    const int ylo = tid >> 4, xq = tid & 15, x0 = xq * 2;

    f16x2 a0; a0[0] = (f16)0; a0[1] = (f16)0;
    f16x2 a1 = a0;
#pragma unroll
    for (int u = 0; u < 5; ++u) {
        const f16x2* row = &pt[ylo + u][x0];
        const f16x2 r0 = row[0], r1 = row[1], r2 = row[2];
        const f16x2 r3 = row[3], r4 = row[4], r5 = row[5];
        a0 += wp[u*5+0] * r0;  a1 += wp[u*5+0] * r1;
        a0 += wp[u*5+1] * r1;  a1 += wp[u*5+1] * r2;
        a0 += wp[u*5+2] * r2;  a1 += wp[u*5+2] * r3;
        a0 += wp[u*5+3] * r3;  a1 += wp[u*5+3] * r4;
        a0 += wp[u*5+4] * r4;  a1 += wp[u*5+4] * r5;
    }

    f16* ob = outp + (size_t)(b * 128 + c) * LL + (size_t)(h0 + ylo) * 160 + (w0 + x0);
    f16x2 lo2; lo2[0] = a0[0]; lo2[1] = a1[0];
    f16x2 hi2; hi2[0] = a0[1]; hi2[1] = a1[1];
    *reinterpret_cast<f16x2*>(ob) = lo2;
    *reinterpret_cast<f16x2*>(ob + 16 * 160) = hi2;
}

// ---------------------------------------------------------------------------
// Attention reduce via MFMA outer product (inputs pre-activated; relu only).
// grid 800 = (b:2, h:16, chunk:25 of 1024 pos), block 256 (4 waves).
// ---------------------------------------------------------------------------
__global__ __launch_bounds__(256) void att_reduce_kernel(
    const f16* __restrict__ ACT, const f16* __restrict__ K2,
    const f16* __restrict__ V2,
    float* __restrict__ kvout, float* __restrict__ ksum)
{
    __shared__ float kvred[4][256];

    const int bx = blockIdx.x;
    const int b = bx / 400;
    const int rem = bx - b * 400;
    const int h = rem / 25;
    const int chunk = rem - h * 25;
    const int tid = threadIdx.x;
    const int wv = tid >> 6, l = tid & 63;
    const int ch = l & 15, kg = l >> 4;
    const bool half1 = h < 8;

    const f16* kbase = half1 ? ACT + (size_t)(b * 256 + h * 16 + ch) * LL
                             : K2 + (size_t)(b * 128 + (h - 8) * 16 + ch) * LL;
    const f16* vbase = half1 ? ACT + (size_t)(b * 256 + 128 + h * 16 + ch) * LL
                             : V2 + (size_t)(b * 128 + (h - 8) * 16 + ch) * LL;

    f32x4 acc = (f32x4){0.f, 0.f, 0.f, 0.f};
    float ksacc = 0.f;
    const int base = chunk * 1024 + kg * 8;
#pragma unroll
    for (int it = 0; it < 8; ++it) {
        const int p = base + wv * 256 + it * 32;
        const f16x8 kf = *reinterpret_cast<const f16x8*>(kbase + p);
        const f16x8 vf = *reinterpret_cast<const f16x8*>(vbase + p);
        f16x8 ka;
#pragma unroll
        for (int j = 0; j < 8; ++j) {
            const f16 kv_ = kf[j];
            ka[j] = (kv_ > (f16)0) ? kv_ : (f16)0;
            ksacc += (float)ka[j];
        }
        acc = __builtin_amdgcn_mfma_f32_16x16x32_f16(ka, vf, acc, 0, 0, 0);
    }

    constexpr float s = 1.f / (float)LL;
#pragma unroll
    for (int r = 0; r < 4; ++r)
        kvred[wv][(kg * 4 + r) * 16 + ch] = acc[r];
    __syncthreads();
    {
        float t = kvred[0][tid] + kvred[1][tid] + kvred[2][tid] + kvred[3][tid];
        atomicAdd(&kvout[(size_t)(b * 16 + h) * 256 + tid], t * s);
    }

    float s1 = ksacc;
    s1 += __shfl_xor(s1, 16);
    s1 += __shfl_xor(s1, 32);
    if (l < 16) atomicAdd(&ksum[(size_t)(b * 16 + h) * 16 + ch], s1 * s);
}

// ---------------------------------------------------------------------------
// Attention apply (inputs pre-activated; relu only).
// grid 3200 = (b:2, h:16, chunk:100 of 256 pos), block 256.
// ---------------------------------------------------------------------------
__global__ __launch_bounds__(256) void att_apply_kernel(
    const f16* __restrict__ Q, const f16* __restrict__ Q2,
    const float* __restrict__ kvin, const float* __restrict__ ksumin,
    f16* __restrict__ att)
{
    __shared__ float kvs[256];
    __shared__ float kss[16];

    const int bx = blockIdx.x;
    const int b = bx / 1600;
    const int rem = bx - b * 1600;
    const int h = rem / 100;
    const int chunk = rem - h * 100;
    const int tid = threadIdx.x;
    const int p = chunk * 256 + tid;

    kvs[tid] = kvin[(size_t)b * 4096 + h * 256 + tid];
    if (tid < 16) kss[tid] = ksumin[(size_t)b * 256 + h * 16 + tid];
    __syncthreads();

    const f16* qb = (h < 8) ? Q + (size_t)(b * 128 + h * 16) * LL
                            : Q2 + (size_t)(b * 128 + (h - 8) * 16) * LL;
    float s[16];
#pragma unroll
    for (int d = 0; d < 16; ++d)
        s[d] = fmaxf((float)qb[(size_t)d * LL + p], 0.f);
    float denom = 0.f;
#pragma unroll
    for (int d = 0; d < 16; ++d) denom = fmaf(s[d], kss[d], denom);
    const float z = 1.f / fmaxf(denom, 1e-6f);

    f16* ob = att + (size_t)(b * 256 + h * 16) * LL + p;
#pragma unroll
    for (int e = 0; e < 16; ++e) {
        float acc = 0.f;
#pragma unroll
        for (int d = 0; d < 16; ++d)
            acc = fmaf(s[d], kvs[d * 16 + e], acc);
        ob[(size_t)e * LL] = (f16)(acc * z);
    }
}

// ---------------------------------------------------------------------------
// Fused tail: t[c] = resid + gelu(bn(yconv)); out = LN_c(t)*w+b.
// VECTORIZED: thread handles 8 consecutive positions (f16x8 / float4x2).
// ---------------------------------------------------------------------------
template <bool RES32, bool OUT32>
__global__ __launch_bounds__(256) void fuse_ln_kernel(
    const f16* __restrict__ yconv, const void* __restrict__ residv,
    const float* __restrict__ stat,
    const float* __restrict__ lnw, const float* __restrict__ lnb,
    void* __restrict__ outv)
{
    __shared__ float t[128][65];
    __shared__ float mrs[128][2];
    __shared__ float red[4][64][2];
    __shared__ float mln[64], rln[64];

    const int bx = blockIdx.x;
    const int b = bx / 400, p0 = (bx - b * 400) * 64;
    const int tid = threadIdx.x;

    if (tid < 128) {
        float m, r;
        stat_mr(stat, 128, tid, m, r);
        mrs[tid][0] = m; mrs[tid][1] = r;
    }
    __syncthreads();

#pragma unroll
    for (int it = 0; it < 4; ++it) {
        const int chunk = it * 256 + tid;
        const int c  = chunk >> 3;
        const int pg = (chunk & 7) * 8;
        const size_t off = (size_t)(b * 128 + c) * LL + p0 + pg;
        const f16x8 yv = *reinterpret_cast<const f16x8*>(yconv + off);
        const float m = mrs[c][0], r = mrs[c][1];
        float rv[8];
        if (RES32) {
            const float* rp = reinterpret_cast<const float*>(residv) + off;
            const float4 ra = *reinterpret_cast<const float4*>(rp);
            const float4 rb = *reinterpret_cast<const float4*>(rp + 4);
            rv[0] = ra.x; rv[1] = ra.y; rv[2] = ra.z; rv[3] = ra.w;
            rv[4] = rb.x; rv[5] = rb.y; rv[6] = rb.z; rv[7] = rb.w;
        } else {
            const f16x8 rr = *reinterpret_cast<const f16x8*>(
                reinterpret_cast<const f16*>(residv) + off);
#pragma unroll
            for (int j = 0; j < 8; ++j) rv[j] = (float)rr[j];
        }
#pragma unroll
        for (int j = 0; j < 8; ++j)
            t[c][pg + j] = gelu_f(((float)yv[j] - m) * r) + rv[j];
    }
    __syncthreads();

    {
        const int i = tid & 63, q = tid >> 6;
        float ps = 0.f, pq = 0.f;
        for (int c = q * 32; c < q * 32 + 32; ++c) {
            const float v = t[c][i];
            ps += v; pq += v * v;
        }
        red[q][i][0] = ps; red[q][i][1] = pq;
    }
    __syncthreads();
    if (tid < 64) {
        float s1 = 0.f, s2 = 0.f;
#pragma unroll
        for (int q = 0; q < 4; ++q) { s1 += red[q][tid][0]; s2 += red[q][tid][1]; }
        const float m = s1 * (1.f / 128.f);
        const float var = s2 * (1.f / 128.f) - m * m;
        mln[tid] = m; rln[tid] = rsqrtf(var + 1e-5f);
    }
    __syncthreads();

#pragma unroll
    for (int it = 0; it < 4; ++it) {
        const int chunk = it * 256 + tid;
        const int c  = chunk >> 3;
        const int pg = (chunk & 7) * 8;
        const size_t off = (size_t)(b * 128 + c) * LL + p0 + pg;
        const float lw = lnw[c], lb = lnb[c];
        if (OUT32) {
            float4 oa, ob2;
            float* op = reinterpret_cast<float*>(outv) + off;
            oa.x = (t[c][pg+0] - mln[pg+0]) * rln[pg+0] * lw + lb;
            oa.y = (t[c][pg+1] - mln[pg+1]) * rln[pg+1] * lw + lb;
            oa.z = (t[c][pg+2] - mln[pg+2]) * rln[pg+2] * lw + lb;
            oa.w = (t[c][pg+3] - mln[pg+3]) * rln[pg+3] * lw + lb;
            ob2.x = (t[c][pg+4] - mln[pg+4]) * rln[pg+4] * lw + lb;
            ob2.y = (t[c][pg+5] - mln[pg+5]) * rln[pg+5] * lw + lb;
            ob2.z = (t[c][pg+6] - mln[pg+6]) * rln[pg+6] * lw + lb;
            ob2.w = (t[c][pg+7] - mln[pg+7]) * rln[pg+7] * lw + lb;
            *reinterpret_cast<float4*>(op) = oa;
            *reinterpret_cast<float4*>(op + 4) = ob2;
        } else {
            f16x8 o;
#pragma unroll
            for (int j = 0; j < 8; ++j)
                o[j] = (f16)((t[c][pg + j] - mln[pg + j]) * rln[pg + j] * lw + lb);
            *reinterpret_cast<f16x8*>(reinterpret_cast<f16*>(outv) + off) = o;
        }
    }
}

// ---------------------------------------------------------------------------
// wcomb[o, c2] = sum_m wmerge[o, m] * wproj[m, c2]  +  zero the stats region.
// grid 128 x 256 (32768 threads >= zcount).
// ---------------------------------------------------------------------------
__global__ __launch_bounds__(256) void wcomb_kernel(
    const float* __restrict__ wmerge, const float* __restrict__ wproj,
    float* __restrict__ wc, float* __restrict__ zbase, int zcount)
{
    const int g = blockIdx.x * 256 + threadIdx.x;
    if (g < zcount) zbase[g] = 0.f;

    const int o = blockIdx.x;
    const int c2 = threadIdx.x;
    float acc = 0.f;
#pragma unroll 4
    for (int m = 0; m < 128; ++m)
        acc = fmaf(wmerge[o * 128 + m], wproj[m * 256 + c2], acc);
    wc[o * 256 + c2] = acc;
}

// ---------------------------------------------------------------------------
extern "C" void kernel_launch(void* const* d_in, const int* in_sizes, int n_in,
                              void* d_out, int out_size, void* d_ws, size_t ws_size,
                              hipStream_t stream)
{
    const float* x      = (const float*)d_in[0];
    const float* source = (const float*)d_in[1];
    const float* wq = (const float*)d_in[2];  const float* bq = (const float*)d_in[3];
    const float* wk = (const float*)d_in[4];  const float* bk = (const float*)d_in[5];
    const float* wvw = (const float*)d_in[6]; const float* bvb = (const float*)d_in[7];
    const float* dwq = (const float*)d_in[8];  const float* pwq = (const float*)d_in[9];
    const float* dwk = (const float*)d_in[10]; const float* pwk = (const float*)d_in[11];
    const float* dwv = (const float*)d_in[12]; const float* pwv = (const float*)d_in[13];
    const float* wproj  = (const float*)d_in[14];
    const float* wmerge = (const float*)d_in[15]; const float* bmerge = (const float*)d_in[16];
    const float* wff1 = (const float*)d_in[17]; const float* bff1 = (const float*)d_in[18];
    const float* wff2 = (const float*)d_in[19]; const float* bff2 = (const float*)d_in[20];
    const float* ln1w = (const float*)d_in[21]; const float* ln1b = (const float*)d_in[22];
    const float* ln2w = (const float*)d_in[23]; const float* ln2b = (const float*)d_in[24];

    const size_t UNIT  = (size_t)2 * 128 * LL;                // 6,553,600 f16
    const size_t UNITB = UNIT * sizeof(f16);                  // 13,107,200 B
    char* w = (char*)d_ws;
    f16* qraw  = (f16*)w; w += UNITB;        // later: dtq
    f16* kvraw = (f16*)w; w += 2 * UNITB;    // later: dtk, dtv
    f16* actq  = (f16*)w; w += UNITB;
    f16* actkv = (f16*)w; w += 2 * UNITB;    // later: att
    f16* q2raw = (f16*)w; w += UNITB;
    f16* k2raw = (f16*)w; w += UNITB;
    f16* v2raw = (f16*)w; w += UNITB;
    f16* y2raw = (f16*)w; w += UNITB;
    f16* msg   = (f16*)w; w += UNITB;
    f16* ff1raw= (f16*)w; w += 2 * UNITB;
    f16* ff2raw= (f16*)w; w += UNITB;

    f16* dtq = qraw;
    f16* dtk = kvraw;
    f16* dtv = kvraw + UNIT;
    f16* att = actkv;

    float* zbase = (float*)w;
    float* kvred = zbase;                      // 8192
    float* ksum  = zbase + 8192;               // 512
    float* sQ    = zbase + 8704;               // NSH*256
    float* sKV   = sQ + NSH * 256;             // NSH*512
    float* sM    = sKV + NSH * 512;            // NSH*256
    float* sF1   = sM + NSH * 256;             // NSH*512
    float* sF2   = sF1 + NSH * 512;            // NSH*256
    const int zcount = 8192 + 512 + NSH * (256 + 512 + 256 + 512 + 256); // 23040
    float* wcomb = zbase + zcount;             // 128*256 fp32

    // zero stats + combine wproj/wmerge in one launch
    wcomb_kernel<<<128, 256, 0, stream>>>(wmerge, wproj, wcomb, zbase, zcount);

    // q / (k,v) 1x1 convs with BN stats  <M,K,PP,NSEG,IN32,LDG,TWOW,BIAS,STATS>
    gemm_kernel<128,128,128,1,true,false,false,true,true><<<400, 512, 0, stream>>>(
        x, nullptr, nullptr, wq, nullptr, nullptr, nullptr, bq, nullptr, nullptr,
        qraw, nullptr, nullptr, sQ);
    gemm_kernel<256,128,64,1,true,false,true,true,true><<<800, 512, 0, stream>>>(
        source, nullptr, nullptr, wk, wvw, nullptr, nullptr, bk, bvb, nullptr,
        kvraw, nullptr, nullptr, sKV);

    // materialize activations once (consumed by dw5 / att_reduce / att_apply)
    act_kernel<<<9600, 256, 0, stream>>>(qraw, kvraw, sQ, sKV, actq, actkv);

    // multiscale branch: 3 depthwise in one launch, 3 pointwise in one launch
    dim3 dwg(5, 5, 768);
    dw5_kernel<<<dwg, 256, 0, stream>>>(actq, actkv, dwq, dwk, dwv, dtq, dtk, dtv);
    gemm_kernel<128,128,128,3,false,false,false,false,false><<<1200, 512, 0, stream>>>(
        dtq, dtk, dtv, pwq, nullptr, pwk, pwv, nullptr, nullptr, nullptr,
        q2raw, k2raw, v2raw, nullptr);

    // linear attention
    att_reduce_kernel<<<800, 256, 0, stream>>>(actkv, k2raw, v2raw, kvred, ksum);
    att_apply_kernel<<<3200, 256, 0, stream>>>(actq, q2raw, kvred, ksum, att);

    // merged (wmerge @ wproj) conv with BN stats
    gemm_kernel<128,256,128,1,false,false,false,true,true><<<400, 512, 0, stream>>>(
        att, nullptr, nullptr, wcomb, nullptr, nullptr, nullptr, bmerge, nullptr,
        nullptr, y2raw, nullptr, nullptr, sM);

    // msg = LN1(x + gelu(bn(y2)))
    fuse_ln_kernel<true,false><<<800, 256, 0, stream>>>(
        y2raw, x, sM, ln1w, ln1b, msg);

    // FFN: ff1 GEMM; ff2 GEMM with BN+GELU fused on load
    gemm_kernel<256,128,64,1,false,false,false,true,true><<<800, 512, 0, stream>>>(
        msg, nullptr, nullptr, wff1, nullptr, nullptr, nullptr, bff1, nullptr,
        nullptr, ff1raw, nullptr, nullptr, sF1);
    gemm_kernel<128,256,128,1,false,true,false,true,true><<<400, 512, 0, stream>>>(
        ff1raw, nullptr, nullptr, wff2, nullptr, nullptr, nullptr, bff2, nullptr,
        sF1, ff2raw, nullptr, nullptr, sF2);

    // out = LN2(msg + gelu(bn(ff2)))
    fuse_ln_kernel<false,true><<<800, 256, 0, stream>>>(
        ff2raw, msg, sF2, ln2w, ln2b, (float*)d_out);
}

// Round 18
// 246.027 us; speedup vs baseline: 1.5192x; 1.0342x over previous
//
#include <hip/hip_runtime.h>
#include <math.h>

#define LL 25600          // H*W
#define NTOTF 51200.f     // B*L (batch-norm N)
#define NSH 8             // stats shadow copies

using f16   = _Float16;
using f16x8 = __attribute__((ext_vector_type(8))) _Float16;
using f16x4 = __attribute__((ext_vector_type(4))) _Float16;
using f16x2 = __attribute__((ext_vector_type(2))) _Float16;
using f32x4 = __attribute__((ext_vector_type(4))) float;

// fast GELU: tanh form, one __expf.  max |err| vs exact erf-gelu ~1e-3.
__device__ __forceinline__ float gelu_f(float v) {
    const float u2 = v * (1.5957691216057308f + 0.0713548162726009f * v * v);
    const float e  = __expf(u2);
    return v * (1.f - 1.f / (e + 1.f));     // v * sigmoid(u2), inf-safe
}

// sum the NSH shadow copies of a [NSH][2C] stats array -> (mean, rstd)
__device__ __forceinline__ void stat_mr(const float* st, int C, int c,
                                        float& m, float& r) {
    float s1 = 0.f, s2 = 0.f;
#pragma unroll
    for (int sh = 0; sh < NSH; ++sh) {
        s1 += st[sh * 2 * C + c];
        s2 += st[sh * 2 * C + C + c];
    }
    m = s1 * (1.f / NTOTF);
    r = rsqrtf(s2 * (1.f / NTOTF) - m * m + 1e-5f);
}

// ---------------------------------------------------------------------------
// f16 MFMA GEMM.  __launch_bounds__(512,2) = 128-VGPR budget.
// LOOP: grid = nchunk/2; block processes 2 chunks with double-buffered Xs;
//   W registers loaded once, next chunk's X loads in flight during MFMA.
// ---------------------------------------------------------------------------
template <int M, int K, int PP, int NSEG, bool LOOP, bool IN32, bool LDG,
          bool TWOW, bool BIAS, bool STATS>
__global__ __launch_bounds__(512, 2) void gemm_kernel(
    const void* __restrict__ X1, const void* __restrict__ X2,
    const void* __restrict__ X3,
    const float* __restrict__ WA, const float* __restrict__ WB,
    const float* __restrict__ W2, const float* __restrict__ W3,
    const float* __restrict__ biasA, const float* __restrict__ biasB,
    const float* __restrict__ lstat,
    f16* __restrict__ Y1, f16* __restrict__ Y2, f16* __restrict__ Y3,
    float* __restrict__ ostat)
{
    constexpr int MR  = M / 128;
    constexpr int KS  = K / 32;
    constexpr int NR  = PP / 16;
    constexpr int PG  = PP / 8;
    constexpr int NCH = (K * PG) / 512;
    constexpr int NCHUNK = LL / PP;
    constexpr int NBUF = LOOP ? 2 : 1;

    __shared__ f16 Xs[NBUF * PP * K];

    const int tid  = threadIdx.x;
    const int lane = tid & 63;
    const int wv   = tid >> 6;
    const int lm16 = lane & 15, lg = lane >> 4;
    const int row0 = wv * (M / 8);

    int bx = blockIdx.x, seg = 0;
    if (NSEG > 1) { seg = bx / (2 * NCHUNK); bx -= seg * 2 * NCHUNK; }

    const void*  Xp = (NSEG > 1) ? (seg == 0 ? X1 : (seg == 1 ? X2 : X3)) : X1;
    const float* Wp = (NSEG > 1) ? (seg == 0 ? WA : (seg == 1 ? W2 : W3)) : WA;
    f16*         Yp = (NSEG > 1) ? (seg == 0 ? Y1 : (seg == 1 ? Y2 : Y3)) : Y1;

    const int c0  = (tid / PG) * NCH;
    const int p0g = (tid % PG) * 8;

    // ---- X chunk loaders (regs) + swizzled LDS store ----
    f16x8 xin[NCH];
    auto load_regs = [&](int t) {
        const int bb  = t / NCHUNK;
        const int pp0 = (t - bb * NCHUNK) * PP;
#pragma unroll
        for (int cc = 0; cc < NCH; ++cc) {
            const size_t roff = (size_t)(bb * K + c0 + cc) * LL + pp0 + p0g;
            if (IN32) {
                const float4 a  = *reinterpret_cast<const float4*>(
                                      reinterpret_cast<const float*>(Xp) + roff);
                const float4 b2 = *reinterpret_cast<const float4*>(
                                      reinterpret_cast<const float*>(Xp) + roff + 4);
                f16x8 v;
                v[0] = (f16)a.x;  v[1] = (f16)a.y;  v[2] = (f16)a.z;  v[3] = (f16)a.w;
                v[4] = (f16)b2.x; v[5] = (f16)b2.y; v[6] = (f16)b2.z; v[7] = (f16)b2.w;
                xin[cc] = v;
            } else {
                xin[cc] = *reinterpret_cast<const f16x8*>(
                              reinterpret_cast<const f16*>(Xp) + roff);
            }
        }
    };
    auto store_lds = [&](int buf) {
        if (LDG) {
#pragma unroll
            for (int cc = 0; cc < NCH; ++cc) {
                const int c = c0 + cc;
                float m, r;
                stat_mr(lstat, K, c, m, r);
#pragma unroll
                for (int j = 0; j < 8; ++j)
                    xin[cc][j] = (f16)gelu_f(((float)xin[cc][j] - m) * r);
            }
        }
#pragma unroll
        for (int j = 0; j < 8; ++j) {
            const int pos = p0g + j;
            const int swz = ((pos & 7) ^ ((pos >> 3) & 7)) << 3;
            f16* base = &Xs[(size_t)buf * PP * K + (size_t)pos * K];
            if constexpr (NCH == 8) {
                f16x8 v;
#pragma unroll
                for (int cc = 0; cc < 8; ++cc) v[cc] = xin[cc][j];
                *reinterpret_cast<f16x8*>(base + (c0 ^ swz)) = v;
            } else if constexpr (NCH == 4) {
                f16x4 v;
#pragma unroll
                for (int cc = 0; cc < 4; ++cc) v[cc] = xin[cc][j];
                *reinterpret_cast<f16x4*>(base + (c0 ^ swz)) = v;
            } else {
                f16x2 v;
#pragma unroll
                for (int cc = 0; cc < 2; ++cc) v[cc] = xin[cc][j];
                *reinterpret_cast<f16x2*>(base + (c0 ^ swz)) = v;
            }
        }
    };

    // ---- W -> registers (B-operand frags), once per block ----
    f16x8 wfr[KS][MR];
#pragma unroll
    for (int k = 0; k < KS; ++k) {
        const int col = k * 32 + lg * 8;
#pragma unroll
        for (int mr = 0; mr < MR; ++mr) {
            const int row = row0 + mr * 16 + lm16;
            const float* wp = (TWOW && row >= 128)
                                  ? WB + (size_t)(row - 128) * K + col
                                  : Wp + (size_t)row * K + col;
            const float4 wa = *reinterpret_cast<const float4*>(wp);
            const float4 wb2 = *reinterpret_cast<const float4*>(wp + 4);
            f16x8 v;
            v[0] = (f16)wa.x; v[1] = (f16)wa.y; v[2] = (f16)wa.z; v[3] = (f16)wa.w;
            v[4] = (f16)wb2.x; v[5] = (f16)wb2.y; v[6] = (f16)wb2.z; v[7] = (f16)wb2.w;
            wfr[k][mr] = v;
        }
    }

    float bvv[MR], st1[MR], st2[MR];
#pragma unroll
    for (int mr = 0; mr < MR; ++mr) {
        const int o = row0 + mr * 16 + lm16;
        bvv[mr] = BIAS ? ((TWOW && o >= 128) ? biasB[o - 128] : biasA[o]) : 0.f;
        st1[mr] = 0.f; st2[mr] = 0.f;
    }

    int t = bx;
    int cur = 0;
    load_regs(t);
    store_lds(0);
    __syncthreads();

    while (true) {
        const int tn = t + gridDim.x;
        const bool nxt = LOOP && (tn < (NSEG > 1 ? 2 * NCHUNK : 2 * NCHUNK));
        if (nxt) load_regs(tn);            // next-chunk global loads in flight

        // ---- MFMA on current buffer ----
        f32x4 acc[MR][NR];
#pragma unroll
        for (int mr = 0; mr < MR; ++mr)
#pragma unroll
            for (int nr = 0; nr < NR; ++nr)
                acc[mr][nr] = (f32x4){0.f, 0.f, 0.f, 0.f};

#pragma unroll
        for (int k = 0; k < KS; ++k) {
            const int kc = k * 32 + lg * 8;
            f16x8 xa[NR];
#pragma unroll
            for (int nr = 0; nr < NR; ++nr) {
                const int pos = nr * 16 + lm16;
                const int swz = ((pos & 7) ^ ((pos >> 3) & 7)) << 3;
                xa[nr] = *reinterpret_cast<const f16x8*>(
                    &Xs[(size_t)cur * PP * K + (size_t)pos * K + (kc ^ swz)]);
            }
#pragma unroll
            for (int mr = 0; mr < MR; ++mr)
#pragma unroll
                for (int nr = 0; nr < NR; ++nr)
                    acc[mr][nr] = __builtin_amdgcn_mfma_f32_16x16x32_f16(
                        xa[nr], wfr[k][mr], acc[mr][nr], 0, 0, 0);
        }

        // ---- epilogue for chunk t ----
        const int bb  = t / NCHUNK;
        const int pp0 = (t - bb * NCHUNK) * PP;
#pragma unroll
        for (int mr = 0; mr < MR; ++mr) {
            const int o = row0 + mr * 16 + lm16;
            f16* yb = Yp + (size_t)(bb * M + o) * LL + pp0;
#pragma unroll
            for (int nr = 0; nr < NR; ++nr) {
                f16x4 o4;
#pragma unroll
                for (int r = 0; r < 4; ++r) {
                    const float v = acc[mr][nr][r] + bvv[mr];
                    o4[r] = (f16)v;
                    if (STATS) { st1[mr] += v; st2[mr] += v * v; }
                }
                *reinterpret_cast<f16x4*>(yb + nr * 16 + lg * 4) = o4;
            }
        }

        if (!nxt) break;
        store_lds(cur ^ 1);
        __syncthreads();
        cur ^= 1; t = tn;
    }

    if (STATS) {
        float* osb = ostat + (size_t)(blockIdx.x & (NSH - 1)) * 2 * M;
#pragma unroll
        for (int mr = 0; mr < MR; ++mr) {
            float s1 = st1[mr], s2 = st2[mr];
            s1 += __shfl_xor(s1, 16); s2 += __shfl_xor(s2, 16);
            s1 += __shfl_xor(s1, 32); s2 += __shfl_xor(s2, 32);
            if (lane < 16) {
                const int o = row0 + mr * 16 + lm16;
                atomicAdd(&osb[o], s1);
                atomicAdd(&osb[M + o], s2);
            }
        }
    }
}

// ---------------------------------------------------------------------------
// Activation pass: actq = gelu(bn(qraw)), actkv = gelu(bn(kvraw)).
// ---------------------------------------------------------------------------
__global__ __launch_bounds__(256) void act_kernel(
    const f16* __restrict__ qraw, const f16* __restrict__ kvraw,
    const float* __restrict__ sQ, const float* __restrict__ sKV,
    f16* __restrict__ actq, f16* __restrict__ actkv)
{
    const int idx = blockIdx.x * 256 + threadIdx.x;
    const f16* src; f16* dst; const float* st; int C, local;
    if (idx < 819200) { src = qraw;  dst = actq;  st = sQ;  C = 128; local = idx; }
    else              { src = kvraw; dst = actkv; st = sKV; C = 256; local = idx - 819200; }
    const int c = (local / 3200) % C;
    float m, r;
    stat_mr(st, C, c, m, r);
    const f16x8 v = *reinterpret_cast<const f16x8*>(src + (size_t)local * 8);
    f16x8 o;
#pragma unroll
    for (int j = 0; j < 8; ++j)
        o[j] = (f16)gelu_f(((float)v[j] - m) * r);
    *reinterpret_cast<f16x8*>(dst + (size_t)local * 8) = o;
}

// ---------------------------------------------------------------------------
// Batched depthwise 5x5 SAME on PRE-ACTIVATED f16 input (round-10/14 version).
// ---------------------------------------------------------------------------
__global__ __launch_bounds__(256) void dw5_kernel(
    const f16* __restrict__ actq, const f16* __restrict__ actkv,
    const float* __restrict__ dwq, const float* __restrict__ dwk,
    const float* __restrict__ dwv,
    f16* __restrict__ oq, f16* __restrict__ ok, f16* __restrict__ ov)
{
    __shared__ f16x2 pt[20][41];
    const int z = blockIdx.z;
    const int which = z >> 8;
    const int bc = z & 255;
    const int b = bc >> 7, c = bc & 127;

    const f16* src; const float* wdwp; f16* outp;
    if (which == 0)      { src = actq  + (size_t)(b * 128 + c) * LL;       wdwp = dwq + c * 25; outp = oq; }
    else if (which == 1) { src = actkv + (size_t)(b * 256 + c) * LL;       wdwp = dwk + c * 25; outp = ok; }
    else                 { src = actkv + (size_t)(b * 256 + 128 + c) * LL; wdwp = dwv + c * 25; outp = ov; }

    const int h0 = blockIdx.y * 32, w0 = blockIdx.x * 32;
    const int tid = threadIdx.x;

    f16x2 wp[25];
#pragma unroll
    for (int q = 0; q < 25; ++q) {
        const f16 wv16 = (f16)wdwp[q];
        wp[q][0] = wv16; wp[q][1] = wv16;
    }

    for (int idx = tid; idx < 720; idx += 256) {
        const int t  = idx / 36, cc = idx - t * 36;
        const int iw = w0 - 2 + cc;
        const int ih0 = h0 - 2 + t, ih1 = ih0 + 16;
        const int iwc  = min(max(iw, 0), 159);
        const int ihc0 = min(max(ih0, 0), 159);
        const int ihc1 = min(max(ih1, 0), 159);
        const bool okw = (iw >= 0) & (iw < 160);
        f16 lo = src[ihc0 * 160 + iwc];
        f16 hi = src[ihc1 * 160 + iwc];
        if (!(okw & (ih0 >= 0) & (ih0 < 160))) lo = (f16)0;
        if (!(okw & (ih1 >= 0) & (ih1 < 160))) hi = (f16)0;
        f16x2 pv; pv[0] = lo; pv[1] = hi;
        pt[t][cc] = pv;
    }
    __syncthreads();

    const int ylo = tid >> 4, xq = tid & 15, x0 = xq * 2;

    f16x2 a0; a0[0] = (f16)0; a0[1] = (f16)0;
    f16x2 a1 = a0;
#pragma unroll
    for (int u = 0; u < 5; ++u) {
        const f16x2* row = &pt[ylo + u][x0];
        const f16x2 r0 = row[0], r1 = row[1], r2 = row[2];
        const f16x2 r3 = row[3], r4 = row[4], r5 = row[5];
        a0 += wp[u*5+0] * r0;  a1 += wp[u*5+0] * r1;
        a0 += wp[u*5+1] * r1;  a1 += wp[u*5+1] * r2;
        a0 += wp[u*5+2] * r2;  a1 += wp[u*5+2] * r3;
        a0 += wp[u*5+3] * r3;  a1 += wp[u*5+3] * r4;
        a0 += wp[u*5+4] * r4;  a1 += wp[u*5+4] * r5;
    }

    f16* ob = outp + (size_t)(b * 128 + c) * LL + (size_t)(h0 + ylo) * 160 + (w0 + x0);
    f16x2 lo2; lo2[0] = a0[0]; lo2[1] = a1[0];
    f16x2 hi2; hi2[0] = a0[1]; hi2[1] = a1[1];
    *reinterpret_cast<f16x2*>(ob) = lo2;
    *reinterpret_cast<f16x2*>(ob + 16 * 160) = hi2;
}

// ---------------------------------------------------------------------------
// Attention reduce via MFMA outer product (inputs pre-activated; relu only).
// ---------------------------------------------------------------------------
__global__ __launch_bounds__(256) void att_reduce_kernel(
    const f16* __restrict__ ACT, const f16* __restrict__ K2,
    const f16* __restrict__ V2,
    float* __restrict__ kvout, float* __restrict__ ksum)
{
    __shared__ float kvred[4][256];

    const int bx = blockIdx.x;
    const int b = bx / 400;
    const int rem = bx - b * 400;
    const int h = rem / 25;
    const int chunk = rem - h * 25;
    const int tid = threadIdx.x;
    const int wv = tid >> 6, l = tid & 63;
    const int ch = l & 15, kg = l >> 4;
    const bool half1 = h < 8;

    const f16* kbase = half1 ? ACT + (size_t)(b * 256 + h * 16 + ch) * LL
                             : K2 + (size_t)(b * 128 + (h - 8) * 16 + ch) * LL;
    const f16* vbase = half1 ? ACT + (size_t)(b * 256 + 128 + h * 16 + ch) * LL
                             : V2 + (size_t)(b * 128 + (h - 8) * 16 + ch) * LL;

    f32x4 acc = (f32x4){0.f, 0.f, 0.f, 0.f};
    float ksacc = 0.f;
    const int base = chunk * 1024 + kg * 8;
#pragma unroll
    for (int it = 0; it < 8; ++it) {
        const int p = base + wv * 256 + it * 32;
        const f16x8 kf = *reinterpret_cast<const f16x8*>(kbase + p);
        const f16x8 vf = *reinterpret_cast<const f16x8*>(vbase + p);
        f16x8 ka;
#pragma unroll
        for (int j = 0; j < 8; ++j) {
            const f16 kv_ = kf[j];
            ka[j] = (kv_ > (f16)0) ? kv_ : (f16)0;
            ksacc += (float)ka[j];
        }
        acc = __builtin_amdgcn_mfma_f32_16x16x32_f16(ka, vf, acc, 0, 0, 0);
    }

    constexpr float s = 1.f / (float)LL;
#pragma unroll
    for (int r = 0; r < 4; ++r)
        kvred[wv][(kg * 4 + r) * 16 + ch] = acc[r];
    __syncthreads();
    {
        float t = kvred[0][tid] + kvred[1][tid] + kvred[2][tid] + kvred[3][tid];
        atomicAdd(&kvout[(size_t)(b * 16 + h) * 256 + tid], t * s);
    }

    float s1 = ksacc;
    s1 += __shfl_xor(s1, 16);
    s1 += __shfl_xor(s1, 32);
    if (l < 16) atomicAdd(&ksum[(size_t)(b * 16 + h) * 16 + ch], s1 * s);
}

// ---------------------------------------------------------------------------
// Attention apply (inputs pre-activated; relu only).
// ---------------------------------------------------------------------------
__global__ __launch_bounds__(256) void att_apply_kernel(
    const f16* __restrict__ Q, const f16* __restrict__ Q2,
    const float* __restrict__ kvin, const float* __restrict__ ksumin,
    f16* __restrict__ att)
{
    __shared__ float kvs[256];
    __shared__ float kss[16];

    const int bx = blockIdx.x;
    const int b = bx / 1600;
    const int rem = bx - b * 1600;
    const int h = rem / 100;
    const int chunk = rem - h * 100;
    const int tid = threadIdx.x;
    const int p = chunk * 256 + tid;

    kvs[tid] = kvin[(size_t)b * 4096 + h * 256 + tid];
    if (tid < 16) kss[tid] = ksumin[(size_t)b * 256 + h * 16 + tid];
    __syncthreads();

    const f16* qb = (h < 8) ? Q + (size_t)(b * 128 + h * 16) * LL
                            : Q2 + (size_t)(b * 128 + (h - 8) * 16) * LL;
    float s[16];
#pragma unroll
    for (int d = 0; d < 16; ++d)
        s[d] = fmaxf((float)qb[(size_t)d * LL + p], 0.f);
    float denom = 0.f;
#pragma unroll
    for (int d = 0; d < 16; ++d) denom = fmaf(s[d], kss[d], denom);
    const float z = 1.f / fmaxf(denom, 1e-6f);

    f16* ob = att + (size_t)(b * 256 + h * 16) * LL + p;
#pragma unroll
    for (int e = 0; e < 16; ++e) {
        float acc = 0.f;
#pragma unroll
        for (int d = 0; d < 16; ++d)
            acc = fmaf(s[d], kvs[d * 16 + e], acc);
        ob[(size_t)e * LL] = (f16)(acc * z);
    }
}

// ---------------------------------------------------------------------------
// Fused tail: t[c] = resid + gelu(bn(yconv)); out = LN_c(t)*w+b.
// ---------------------------------------------------------------------------
template <bool RES32, bool OUT32>
__global__ __launch_bounds__(256) void fuse_ln_kernel(
    const f16* __restrict__ yconv, const void* __restrict__ residv,
    const float* __restrict__ stat,
    const float* __restrict__ lnw, const float* __restrict__ lnb,
    void* __restrict__ outv)
{
    __shared__ float t[128][65];
    __shared__ float mrs[128][2];
    __shared__ float red[4][64][2];
    __shared__ float mln[64], rln[64];

    const int bx = blockIdx.x;
    const int b = bx / 400, p0 = (bx - b * 400) * 64;
    const int tid = threadIdx.x;

    if (tid < 128) {
        float m, r;
        stat_mr(stat, 128, tid, m, r);
        mrs[tid][0] = m; mrs[tid][1] = r;
    }
    __syncthreads();

#pragma unroll
    for (int it = 0; it < 4; ++it) {
        const int chunk = it * 256 + tid;
        const int c  = chunk >> 3;
        const int pg = (chunk & 7) * 8;
        const size_t off = (size_t)(b * 128 + c) * LL + p0 + pg;
        const f16x8 yv = *reinterpret_cast<const f16x8*>(yconv + off);
        const float m = mrs[c][0], r = mrs[c][1];
        float rv[8];
        if (RES32) {
            const float* rp = reinterpret_cast<const float*>(residv) + off;
            const float4 ra = *reinterpret_cast<const float4*>(rp);
            const float4 rb = *reinterpret_cast<const float4*>(rp + 4);
            rv[0] = ra.x; rv[1] = ra.y; rv[2] = ra.z; rv[3] = ra.w;
            rv[4] = rb.x; rv[5] = rb.y; rv[6] = rb.z; rv[7] = rb.w;
        } else {
            const f16x8 rr = *reinterpret_cast<const f16x8*>(
                reinterpret_cast<const f16*>(residv) + off);
#pragma unroll
            for (int j = 0; j < 8; ++j) rv[j] = (float)rr[j];
        }
#pragma unroll
        for (int j = 0; j < 8; ++j)
            t[c][pg + j] = gelu_f(((float)yv[j] - m) * r) + rv[j];
    }
    __syncthreads();

    {
        const int i = tid & 63, q = tid >> 6;
        float ps = 0.f, pq = 0.f;
        for (int c = q * 32; c < q * 32 + 32; ++c) {
            const float v = t[c][i];
            ps += v; pq += v * v;
        }
        red[q][i][0] = ps; red[q][i][1] = pq;
    }
    __syncthreads();
    if (tid < 64) {
        float s1 = 0.f, s2 = 0.f;
#pragma unroll
        for (int q = 0; q < 4; ++q) { s1 += red[q][tid][0]; s2 += red[q][tid][1]; }
        const float m = s1 * (1.f / 128.f);
        const float var = s2 * (1.f / 128.f) - m * m;
        mln[tid] = m; rln[tid] = rsqrtf(var + 1e-5f);
    }
    __syncthreads();

#pragma unroll
    for (int it = 0; it < 4; ++it) {
        const int chunk = it * 256 + tid;
        const int c  = chunk >> 3;
        const int pg = (chunk & 7) * 8;
        const size_t off = (size_t)(b * 128 + c) * LL + p0 + pg;
        const float lw = lnw[c], lb = lnb[c];
        if (OUT32) {
            float4 oa, ob2;
            float* op = reinterpret_cast<float*>(outv) + off;
            oa.x = (t[c][pg+0] - mln[pg+0]) * rln[pg+0] * lw + lb;
            oa.y = (t[c][pg+1] - mln[pg+1]) * rln[pg+1] * lw + lb;
            oa.z = (t[c][pg+2] - mln[pg+2]) * rln[pg+2] * lw + lb;
            oa.w = (t[c][pg+3] - mln[pg+3]) * rln[pg+3] * lw + lb;
            ob2.x = (t[c][pg+4] - mln[pg+4]) * rln[pg+4] * lw + lb;
            ob2.y = (t[c][pg+5] - mln[pg+5]) * rln[pg+5] * lw + lb;
            ob2.z = (t[c][pg+6] - mln[pg+6]) * rln[pg+6] * lw + lb;
            ob2.w = (t[c][pg+7] - mln[pg+7]) * rln[pg+7] * lw + lb;
            *reinterpret_cast<float4*>(op) = oa;
            *reinterpret_cast<float4*>(op + 4) = ob2;
        } else {
            f16x8 o;
#pragma unroll
            for (int j = 0; j < 8; ++j)
                o[j] = (f16)((t[c][pg + j] - mln[pg + j]) * rln[pg + j] * lw + lb);
            *reinterpret_cast<f16x8*>(reinterpret_cast<f16*>(outv) + off) = o;
        }
    }
}

// ---------------------------------------------------------------------------
// wcomb[o, c2] = sum_m wmerge[o, m] * wproj[m, c2]  +  zero the stats region.
// ---------------------------------------------------------------------------
__global__ __launch_bounds__(256) void wcomb_kernel(
    const float* __restrict__ wmerge, const float* __restrict__ wproj,
    float* __restrict__ wc, float* __restrict__ zbase, int zcount)
{
    const int g = blockIdx.x * 256 + threadIdx.x;
    if (g < zcount) zbase[g] = 0.f;

    const int o = blockIdx.x;
    const int c2 = threadIdx.x;
    float acc = 0.f;
#pragma unroll 4
    for (int m = 0; m < 128; ++m)
        acc = fmaf(wmerge[o * 128 + m], wproj[m * 256 + c2], acc);
    wc[o * 256 + c2] = acc;
}

// ---------------------------------------------------------------------------
extern "C" void kernel_launch(void* const* d_in, const int* in_sizes, int n_in,
                              void* d_out, int out_size, void* d_ws, size_t ws_size,
                              hipStream_t stream)
{
    const float* x      = (const float*)d_in[0];
    const float* source = (const float*)d_in[1];
    const float* wq = (const float*)d_in[2];  const float* bq = (const float*)d_in[3];
    const float* wk = (const float*)d_in[4];  const float* bk = (const float*)d_in[5];
    const float* wvw = (const float*)d_in[6]; const float* bvb = (const float*)d_in[7];
    const float* dwq = (const float*)d_in[8];  const float* pwq = (const float*)d_in[9];
    const float* dwk = (const float*)d_in[10]; const float* pwk = (const float*)d_in[11];
    const float* dwv = (const float*)d_in[12]; const float* pwv = (const float*)d_in[13];
    const float* wproj  = (const float*)d_in[14];
    const float* wmerge = (const float*)d_in[15]; const float* bmerge = (const float*)d_in[16];
    const float* wff1 = (const float*)d_in[17]; const float* bff1 = (const float*)d_in[18];
    const float* wff2 = (const float*)d_in[19]; const float* bff2 = (const float*)d_in[20];
    const float* ln1w = (const float*)d_in[21]; const float* ln1b = (const float*)d_in[22];
    const float* ln2w = (const float*)d_in[23]; const float* ln2b = (const float*)d_in[24];

    const size_t UNIT  = (size_t)2 * 128 * LL;                // 6,553,600 f16
    const size_t UNITB = UNIT * sizeof(f16);                  // 13,107,200 B
    char* w = (char*)d_ws;
    f16* qraw  = (f16*)w; w += UNITB;        // later: dtq
    f16* kvraw = (f16*)w; w += 2 * UNITB;    // later: dtk, dtv
    f16* actq  = (f16*)w; w += UNITB;
    f16* actkv = (f16*)w; w += 2 * UNITB;    // later: att
    f16* q2raw = (f16*)w; w += UNITB;
    f16* k2raw = (f16*)w; w += UNITB;
    f16* v2raw = (f16*)w; w += UNITB;
    f16* y2raw = (f16*)w; w += UNITB;
    f16* msg   = (f16*)w; w += UNITB;
    f16* ff1raw= (f16*)w; w += 2 * UNITB;
    f16* ff2raw= (f16*)w; w += UNITB;

    f16* dtq = qraw;
    f16* dtk = kvraw;
    f16* dtv = kvraw + UNIT;
    f16* att = actkv;

    float* zbase = (float*)w;
    float* kvred = zbase;                      // 8192
    float* ksum  = zbase + 8192;               // 512
    float* sQ    = zbase + 8704;               // NSH*256
    float* sKV   = sQ + NSH * 256;             // NSH*512
    float* sM    = sKV + NSH * 512;            // NSH*256
    float* sF1   = sM + NSH * 256;             // NSH*512
    float* sF2   = sF1 + NSH * 512;            // NSH*256
    const int zcount = 8192 + 512 + NSH * (256 + 512 + 256 + 512 + 256); // 23040
    float* wcomb = zbase + zcount;             // 128*256 fp32

    // zero stats + combine wproj/wmerge in one launch
    wcomb_kernel<<<128, 256, 0, stream>>>(wmerge, wproj, wcomb, zbase, zcount);

    // q / (k,v) 1x1 convs with BN stats <M,K,PP,NSEG,LOOP,IN32,LDG,TWOW,BIAS,STATS>
    gemm_kernel<128,128,128,1,false,true,false,false,true,true><<<400, 512, 0, stream>>>(
        x, nullptr, nullptr, wq, nullptr, nullptr, nullptr, bq, nullptr, nullptr,
        qraw, nullptr, nullptr, sQ);
    gemm_kernel<256,128,64,1,true,true,false,true,true,true><<<400, 512, 0, stream>>>(
        source, nullptr, nullptr, wk, wvw, nullptr, nullptr, bk, bvb, nullptr,
        kvraw, nullptr, nullptr, sKV);

    // materialize activations once (consumed by dw5 / att_reduce / att_apply)
    act_kernel<<<9600, 256, 0, stream>>>(qraw, kvraw, sQ, sKV, actq, actkv);

    // multiscale branch: 3 depthwise in one launch, 3 pointwise in one launch
    dim3 dwg(5, 5, 768);
    dw5_kernel<<<dwg, 256, 0, stream>>>(actq, actkv, dwq, dwk, dwv, dtq, dtk, dtv);
    gemm_kernel<128,128,128,3,false,false,false,false,false,false><<<1200, 512, 0, stream>>>(
        dtq, dtk, dtv, pwq, nullptr, pwk, pwv, nullptr, nullptr, nullptr,
        q2raw, k2raw, v2raw, nullptr);

    // linear attention
    att_reduce_kernel<<<800, 256, 0, stream>>>(actkv, k2raw, v2raw, kvred, ksum);
    att_apply_kernel<<<3200, 256, 0, stream>>>(actq, q2raw, kvred, ksum, att);

    // merged (wmerge @ wproj) conv with BN stats
    gemm_kernel<128,256,128,1,false,false,false,false,true,true><<<400, 512, 0, stream>>>(
        att, nullptr, nullptr, wcomb, nullptr, nullptr, nullptr, bmerge, nullptr,
        nullptr, y2raw, nullptr, nullptr, sM);

    // msg = LN1(x + gelu(bn(y2)))
    fuse_ln_kernel<true,false><<<800, 256, 0, stream>>>(
        y2raw, x, sM, ln1w, ln1b, msg);

    // FFN: ff1 GEMM (double-buffered loop); ff2 GEMM with BN+GELU on load
    gemm_kernel<256,128,64,1,true,false,false,false,true,true><<<400, 512, 0, stream>>>(
        msg, nullptr, nullptr, wff1, nullptr, nullptr, nullptr, bff1, nullptr,
        nullptr, ff1raw, nullptr, nullptr, sF1);
    gemm_kernel<128,256,128,1,false,false,true,false,true,true><<<400, 512, 0, stream>>>(
        ff1raw, nullptr, nullptr, wff2, nullptr, nullptr, nullptr, bff2, nullptr,
        sF1, ff2raw, nullptr, nullptr, sF2);

    // out = LN2(msg + gelu(bn(ff2)))
    fuse_ln_kernel<false,true><<<800, 256, 0, stream>>>(
        ff2raw, msg, sF2, ln2w, ln2b, (float*)d_out);
}